// Round 2
// baseline (379.928 us; speedup 1.0000x reference)
//
#include <hip/hip_runtime.h>
#include <stdint.h>

// LSTM fused: B=8192, T=128, I=32, H=64, OUT=8. fp32 internal state, bf16 MFMA.
// Runtime dtype sniff: inputs may be fp32 or bf16 (harness ambiguity); detect
// from x's uint16 halves (fp32 mantissa halves decode as huge/NaN bf16s).
// Each workgroup (256 thr, 4 waves) owns B_TILE=16 batches, runs full T loop.
// Wave w owns hidden units [16w,16w+16); C/D layout col=lane&15 = unit, so each
// thread holds matching i/f/g/o fragments and updates c,h in registers.
// Recurrent h enters MFMA as bf16 hi+lo split (fp32-grade recurrent precision).

#define T_STEPS 128
#define ISZ 32
#define HSZ 64
#define B_TOT 8192
#define B_TILE 16
#define T_CHUNK 32

typedef short bf16x8 __attribute__((ext_vector_type(8)));
typedef float f32x4 __attribute__((ext_vector_type(4)));

__device__ __forceinline__ float bf2f(unsigned short s) {
    union { unsigned int u; float f; } v; v.u = ((unsigned int)s) << 16; return v.f;
}
__device__ __forceinline__ unsigned short f2bf(float f) {
    union { float f; unsigned int u; } v; v.f = f;
    unsigned int u = v.u;
    return (unsigned short)((u + 0x7fffu + ((u >> 16) & 1u)) >> 16);  // RNE
}
// overflow-safe: exp->inf gives 1/(1+inf)=0; exp->0 gives 1
__device__ __forceinline__ float sigf(float x) { return 1.0f / (1.0f + __expf(-x)); }
// overflow-safe: exp(2x)->inf gives 1-0=1; ->0 gives 1-2=-1
__device__ __forceinline__ float tanh_fast(float x) { return 1.0f - 2.0f / (1.0f + __expf(2.0f * x)); }

template <bool F32>
__device__ __forceinline__ float ldin(const void* p, size_t i) {
    if (F32) return ((const float*)p)[i];
    return bf2f(((const unsigned short*)p)[i]);
}

template <bool F32>
__device__ __forceinline__ void run_body(
    const void* xv, const void* Wihv, const void* Whhv, const void* bihv,
    const void* bhhv, const void* Wfcv, const void* bfcv, void* outv,
    unsigned short (&hbuf)[2][B_TILE][136],
    unsigned short (&xbuf)[T_CHUNK][B_TILE][40],
    float (&hfin)[B_TILE][HSZ + 4])
{
    const int tid  = threadIdx.x;
    const int wid  = tid >> 6;
    const int lane = tid & 63;
    const int q    = lane >> 4;   // A/B frag k-quad; C/D row-quad
    const int tn   = lane & 15;   // A: batch row m; B/C: unit col n
    const int u    = wid * 16 + tn;
    const int b0   = blockIdx.x * B_TILE;

    // B-operand weight frags, loaded once. B[k=q*8+j][n=tn], weight row = g*64+u.
    // wf[g][0,1] = W_hh k-tiles (reused by the h_lo split), wf[g][2] = W_ih.
    bf16x8 wf[4][3];
    float bias[4];
    #pragma unroll
    for (int g = 0; g < 4; ++g) {
        const int row = g * HSZ + u;
        #pragma unroll
        for (int j = 0; j < 8; ++j) {
            wf[g][0][j] = (short)f2bf(ldin<F32>(Whhv, row * HSZ + q * 8 + j));
            wf[g][1][j] = (short)f2bf(ldin<F32>(Whhv, row * HSZ + 32 + q * 8 + j));
            wf[g][2][j] = (short)f2bf(ldin<F32>(Wihv, row * ISZ + q * 8 + j));
        }
        bias[g] = ldin<F32>(bihv, row) + ldin<F32>(bhhv, row);
    }

    // h(0) = 0
    for (int i = tid; i < 2 * B_TILE * 136; i += 256) ((unsigned short*)hbuf)[i] = 0;

    float cst[4] = {0.f, 0.f, 0.f, 0.f};
    float hl[4]  = {0.f, 0.f, 0.f, 0.f};

    for (int tc = 0; tc < T_STEPS / T_CHUNK; ++tc) {
        // stage x[b0..+16)[tc*32..+32)[0..32) -> xbuf[t][m][k]; prev chunk's
        // reads finished at the last step's barrier, so no barrier needed here.
        if (F32) {
            const float* xf = (const float*)xv;
            for (int idx = tid; idx < B_TILE * T_CHUNK * 4; idx += 256) {
                const int m  = idx >> 7;
                const int rm = idx & 127;
                const int tl = rm >> 2;
                const int ch = rm & 3;
                const size_t base = ((size_t)(b0 + m) * T_STEPS + (tc * T_CHUNK + tl)) * ISZ + ch * 8;
                const f32x4 v0 = *(const f32x4*)(xf + base);
                const f32x4 v1 = *(const f32x4*)(xf + base + 4);
                bf16x8 w;
                #pragma unroll
                for (int j = 0; j < 4; ++j) {
                    w[j]     = (short)f2bf(v0[j]);
                    w[4 + j] = (short)f2bf(v1[j]);
                }
                *(bf16x8*)&xbuf[tl][m][ch * 8] = w;
            }
        } else {
            const unsigned short* xu = (const unsigned short*)xv;
            for (int idx = tid; idx < B_TILE * T_CHUNK * 4; idx += 256) {
                const int m  = idx >> 7;
                const int rm = idx & 127;
                const int tl = rm >> 2;
                const int ch = rm & 3;
                const uint4 v = *(const uint4*)(xu + ((size_t)(b0 + m) * T_STEPS + (tc * T_CHUNK + tl)) * ISZ + ch * 8);
                *(uint4*)&xbuf[tl][m][ch * 8] = v;
            }
        }
        __syncthreads();

        #pragma unroll 2
        for (int tl = 0; tl < T_CHUNK; ++tl) {
            const int t  = tc * T_CHUNK + tl;
            const int rb = t & 1, wb = rb ^ 1;
            // A frags: A[m=tn][k=q*8+j]
            const bf16x8 a0 = *(const bf16x8*)&hbuf[rb][tn][q * 8];       // h_hi k0..31
            const bf16x8 a1 = *(const bf16x8*)&hbuf[rb][tn][32 + q * 8];  // h_hi k32..63
            const bf16x8 a2 = *(const bf16x8*)&hbuf[rb][tn][64 + q * 8];  // h_lo k0..31
            const bf16x8 a3 = *(const bf16x8*)&hbuf[rb][tn][96 + q * 8];  // h_lo k32..63
            const bf16x8 ax = *(const bf16x8*)&xbuf[tl][tn][q * 8];       // x

            f32x4 acc[4];
            #pragma unroll
            for (int g = 0; g < 4; ++g) {
                #pragma unroll
                for (int e = 0; e < 4; ++e) acc[g][e] = 0.f;
                acc[g] = __builtin_amdgcn_mfma_f32_16x16x32_bf16(a0, wf[g][0], acc[g], 0, 0, 0);
                acc[g] = __builtin_amdgcn_mfma_f32_16x16x32_bf16(a1, wf[g][1], acc[g], 0, 0, 0);
                acc[g] = __builtin_amdgcn_mfma_f32_16x16x32_bf16(a2, wf[g][0], acc[g], 0, 0, 0);
                acc[g] = __builtin_amdgcn_mfma_f32_16x16x32_bf16(a3, wf[g][1], acc[g], 0, 0, 0);
                acc[g] = __builtin_amdgcn_mfma_f32_16x16x32_bf16(ax, wf[g][2], acc[g], 0, 0, 0);
            }
            #pragma unroll
            for (int r = 0; r < 4; ++r) {
                const float gi = sigf(acc[0][r] + bias[0]);
                const float gf = sigf(acc[1][r] + bias[1]);
                const float gg = tanh_fast(acc[2][r] + bias[2]);
                const float go = sigf(acc[3][r] + bias[3]);
                cst[r] = gf * cst[r] + gi * gg;
                const float hv = go * tanh_fast(cst[r]);
                hl[r] = hv;
                const unsigned short hi = f2bf(hv);
                const unsigned short lo = f2bf(hv - bf2f(hi));
                const int m = q * 4 + r;  // C/D row = batch
                hbuf[wb][m][u]      = hi;
                hbuf[wb][m][64 + u] = lo;
            }
            __syncthreads();
        }
    }

    // epilogue: out[b][j] = h_T(fp32) . Wfc[j,:] + bfc[j]
    #pragma unroll
    for (int r = 0; r < 4; ++r) hfin[q * 4 + r][u] = hl[r];
    __syncthreads();
    if (tid < B_TILE * 8) {
        const int m = tid >> 3, j = tid & 7;
        float s = ldin<F32>(bfcv, j);
        #pragma unroll
        for (int k = 0; k < HSZ; ++k) s += hfin[m][k] * ldin<F32>(Wfcv, j * HSZ + k);
        const size_t o = (size_t)(b0 + m) * 8 + j;
        if (F32) ((float*)outv)[o] = s;
        else     ((unsigned short*)outv)[o] = f2bf(s);
    }
}

__global__ __launch_bounds__(256, 2) void lstm_fused(
    const void* __restrict__ x, const void* __restrict__ Wih,
    const void* __restrict__ Whh, const void* __restrict__ bih,
    const void* __restrict__ bhh, const void* __restrict__ Wfc,
    const void* __restrict__ bfc, void* __restrict__ out)
{
    __shared__ unsigned short hbuf[2][B_TILE][136];   // [buf][m][k]: 0..63 h_hi, 64..127 h_lo (+pad)
    __shared__ unsigned short xbuf[T_CHUNK][B_TILE][40];
    __shared__ float hfin[B_TILE][HSZ + 4];

    // dtype sniff: fp32 data read as uint16 halves has mantissa-garbage halves
    // that decode to huge-exponent bf16s; real bf16 N(0,1)/uniform data never
    // exceeds exponent 0x90 (2^17). Block-uniform (all waves sample same addrs).
    const unsigned short* xu = (const unsigned short*)x;
    const int lane = threadIdx.x & 63;
    const unsigned short s0 = xu[lane * 2];
    const unsigned short s1 = xu[lane * 2 + 1];
    const int big = (((s0 >> 7) & 0xFF) >= 0x90) || (((s1 >> 7) & 0xFF) >= 0x90);
    const bool isf32 = __any(big) != 0;

    if (isf32) run_body<true >(x, Wih, Whh, bih, bhh, Wfc, bfc, out, hbuf, xbuf, hfin);
    else       run_body<false>(x, Wih, Whh, bih, bhh, Wfc, bfc, out, hbuf, xbuf, hfin);
}

extern "C" void kernel_launch(void* const* d_in, const int* in_sizes, int n_in,
                              void* d_out, int out_size, void* d_ws, size_t ws_size,
                              hipStream_t stream) {
    lstm_fused<<<dim3(B_TOT / B_TILE), dim3(256), 0, stream>>>(
        d_in[0], d_in[1], d_in[2], d_in[3], d_in[4], d_in[5], d_in[6], d_out);
}

// Round 3
// 288.644 us; speedup vs baseline: 1.3163x; 1.3163x over previous
//
#include <hip/hip_runtime.h>
#include <stdint.h>

// LSTM fused: B=8192, T=128, I=32, H=64, OUT=8. fp32 internal state, bf16 MFMA.
// Inputs verified bf16 (R2 FETCH=66MB == x in bf16); runtime dtype sniff kept as guard.
// Workgroup (256 thr, 4 waves) owns B_TILE=16 batches, runs full T loop.
// Wave w owns hidden units [16w,16w+16); C/D col=lane&15 = unit, so each thread
// holds matching i/f/g/o fragments and updates c,h in registers.
// Recurrent h enters MFMA as bf16 hi+lo split (fp32-grade recurrent precision).
// R3: activations via raw v_exp_f32/v_rcp_f32 (no fp32 div sequences),
//     bias folded into acc init, hbuf row pad 136->144 (disjoint write banks).

#define T_STEPS 128
#define ISZ 32
#define HSZ 64
#define B_TOT 8192
#define B_TILE 16
#define T_CHUNK 32
#define HPAD 144   // row pad: 144 shorts = 72 dwords; q-rows land on banks 8q..8q+7 (disjoint)

typedef short bf16x8 __attribute__((ext_vector_type(8)));
typedef float f32x4 __attribute__((ext_vector_type(4)));

#define LOG2E 1.44269504088896340736f

__device__ __forceinline__ float bf2f(unsigned short s) {
    union { unsigned int u; float f; } v; v.u = ((unsigned int)s) << 16; return v.f;
}
__device__ __forceinline__ unsigned short f2bf(float f) {
    union { float f; unsigned int u; } v; v.f = f;
    unsigned int u = v.u;
    return (unsigned short)((u + 0x7fffu + ((u >> 16) & 1u)) >> 16);  // RNE
}
// sigmoid = rcp(1 + exp2(-x*log2e)); x->-inf: exp2->inf, rcp->0; x->+inf: exp2->0 -> 1. Safe.
__device__ __forceinline__ float sigf(float x) {
    return __builtin_amdgcn_rcpf(1.0f + __builtin_amdgcn_exp2f(-LOG2E * x));
}
// tanh = 1 - 2*rcp(1 + exp2(2x*log2e)); +inf -> 1-0=1; -inf -> 1-2=-1. Safe.
__device__ __forceinline__ float tanh_fast(float x) {
    return 1.0f - 2.0f * __builtin_amdgcn_rcpf(1.0f + __builtin_amdgcn_exp2f((2.0f * LOG2E) * x));
}

template <bool F32>
__device__ __forceinline__ float ldin(const void* p, size_t i) {
    if (F32) return ((const float*)p)[i];
    return bf2f(((const unsigned short*)p)[i]);
}

template <bool F32>
__device__ __forceinline__ void run_body(
    const void* xv, const void* Wihv, const void* Whhv, const void* bihv,
    const void* bhhv, const void* Wfcv, const void* bfcv, void* outv,
    unsigned short (&hbuf)[2][B_TILE][HPAD],
    unsigned short (&xbuf)[T_CHUNK][B_TILE][40],
    float (&hfin)[B_TILE][HSZ + 4])
{
    const int tid  = threadIdx.x;
    const int wid  = tid >> 6;
    const int lane = tid & 63;
    const int q    = lane >> 4;   // A/B frag k-quad; C/D row-quad
    const int tn   = lane & 15;   // A: batch row m; B/C: unit col n
    const int u    = wid * 16 + tn;
    const int b0   = blockIdx.x * B_TILE;

    // B-operand weight frags, loaded once. B[k=q*8+j][n=tn], weight row = g*64+u.
    // wf[g][0,1] = W_hh k-tiles (reused by the h_lo split), wf[g][2] = W_ih.
    bf16x8 wf[4][3];
    float bias[4];
    #pragma unroll
    for (int g = 0; g < 4; ++g) {
        const int row = g * HSZ + u;
        #pragma unroll
        for (int j = 0; j < 8; ++j) {
            wf[g][0][j] = (short)f2bf(ldin<F32>(Whhv, row * HSZ + q * 8 + j));
            wf[g][1][j] = (short)f2bf(ldin<F32>(Whhv, row * HSZ + 32 + q * 8 + j));
            wf[g][2][j] = (short)f2bf(ldin<F32>(Wihv, row * ISZ + q * 8 + j));
        }
        bias[g] = ldin<F32>(bihv, row) + ldin<F32>(bhhv, row);
    }

    // h(0) = 0
    for (int i = tid; i < 2 * B_TILE * HPAD; i += 256) ((unsigned short*)hbuf)[i] = 0;

    float cst[4] = {0.f, 0.f, 0.f, 0.f};
    float hl[4]  = {0.f, 0.f, 0.f, 0.f};

    for (int tc = 0; tc < T_STEPS / T_CHUNK; ++tc) {
        // stage x[b0..+16)[tc*32..+32)[0..32) -> xbuf[t][m][k]; prev chunk's
        // reads finished at the last step's barrier, so no barrier needed here.
        if (F32) {
            const float* xf = (const float*)xv;
            for (int idx = tid; idx < B_TILE * T_CHUNK * 4; idx += 256) {
                const int m  = idx >> 7;
                const int rm = idx & 127;
                const int tl = rm >> 2;
                const int ch = rm & 3;
                const size_t base = ((size_t)(b0 + m) * T_STEPS + (tc * T_CHUNK + tl)) * ISZ + ch * 8;
                const f32x4 v0 = *(const f32x4*)(xf + base);
                const f32x4 v1 = *(const f32x4*)(xf + base + 4);
                bf16x8 w;
                #pragma unroll
                for (int j = 0; j < 4; ++j) {
                    w[j]     = (short)f2bf(v0[j]);
                    w[4 + j] = (short)f2bf(v1[j]);
                }
                *(bf16x8*)&xbuf[tl][m][ch * 8] = w;
            }
        } else {
            const unsigned short* xu = (const unsigned short*)xv;
            for (int idx = tid; idx < B_TILE * T_CHUNK * 4; idx += 256) {
                const int m  = idx >> 7;
                const int rm = idx & 127;
                const int tl = rm >> 2;
                const int ch = rm & 3;
                const uint4 v = *(const uint4*)(xu + ((size_t)(b0 + m) * T_STEPS + (tc * T_CHUNK + tl)) * ISZ + ch * 8);
                *(uint4*)&xbuf[tl][m][ch * 8] = v;
            }
        }
        __syncthreads();

        #pragma unroll 2
        for (int tl = 0; tl < T_CHUNK; ++tl) {
            const int t  = tc * T_CHUNK + tl;
            const int rb = t & 1, wb = rb ^ 1;
            // A frags: A[m=tn][k=q*8+j]
            const bf16x8 a0 = *(const bf16x8*)&hbuf[rb][tn][q * 8];       // h_hi k0..31
            const bf16x8 a1 = *(const bf16x8*)&hbuf[rb][tn][32 + q * 8];  // h_hi k32..63
            const bf16x8 a2 = *(const bf16x8*)&hbuf[rb][tn][64 + q * 8];  // h_lo k0..31
            const bf16x8 a3 = *(const bf16x8*)&hbuf[rb][tn][96 + q * 8];  // h_lo k32..63
            const bf16x8 ax = *(const bf16x8*)&xbuf[tl][tn][q * 8];       // x

            f32x4 acc[4];
            #pragma unroll
            for (int g = 0; g < 4; ++g) {
                #pragma unroll
                for (int e = 0; e < 4; ++e) acc[g][e] = bias[g];  // bias folded into init
                acc[g] = __builtin_amdgcn_mfma_f32_16x16x32_bf16(a0, wf[g][0], acc[g], 0, 0, 0);
                acc[g] = __builtin_amdgcn_mfma_f32_16x16x32_bf16(a1, wf[g][1], acc[g], 0, 0, 0);
                acc[g] = __builtin_amdgcn_mfma_f32_16x16x32_bf16(a2, wf[g][0], acc[g], 0, 0, 0);
                acc[g] = __builtin_amdgcn_mfma_f32_16x16x32_bf16(a3, wf[g][1], acc[g], 0, 0, 0);
                acc[g] = __builtin_amdgcn_mfma_f32_16x16x32_bf16(ax, wf[g][2], acc[g], 0, 0, 0);
            }
            #pragma unroll
            for (int r = 0; r < 4; ++r) {
                const float gi = sigf(acc[0][r]);
                const float gf = sigf(acc[1][r]);
                const float gg = tanh_fast(acc[2][r]);
                const float go = sigf(acc[3][r]);
                cst[r] = gf * cst[r] + gi * gg;
                const float hv = go * tanh_fast(cst[r]);
                hl[r] = hv;
                const unsigned short hi = f2bf(hv);
                const unsigned short lo = f2bf(hv - bf2f(hi));
                const int m = q * 4 + r;  // C/D row = batch
                hbuf[wb][m][u]      = hi;
                hbuf[wb][m][64 + u] = lo;
            }
            __syncthreads();
        }
    }

    // epilogue: out[b][j] = h_T(fp32) . Wfc[j,:] + bfc[j]
    #pragma unroll
    for (int r = 0; r < 4; ++r) hfin[q * 4 + r][u] = hl[r];
    __syncthreads();
    if (tid < B_TILE * 8) {
        const int m = tid >> 3, j = tid & 7;
        float s = ldin<F32>(bfcv, j);
        #pragma unroll
        for (int k = 0; k < HSZ; ++k) s += hfin[m][k] * ldin<F32>(Wfcv, j * HSZ + k);
        const size_t o = (size_t)(b0 + m) * 8 + j;
        if (F32) ((float*)outv)[o] = s;
        else     ((unsigned short*)outv)[o] = f2bf(s);
    }
}

__global__ __launch_bounds__(256, 2) void lstm_fused(
    const void* __restrict__ x, const void* __restrict__ Wih,
    const void* __restrict__ Whh, const void* __restrict__ bih,
    const void* __restrict__ bhh, const void* __restrict__ Wfc,
    const void* __restrict__ bfc, void* __restrict__ out)
{
    __shared__ unsigned short hbuf[2][B_TILE][HPAD];   // [buf][m][k]: 0..63 h_hi, 64..127 h_lo (+pad)
    __shared__ unsigned short xbuf[T_CHUNK][B_TILE][40];
    __shared__ float hfin[B_TILE][HSZ + 4];

    // dtype sniff (guard): fp32 data read as uint16 halves has mantissa-garbage
    // halves decoding to huge-exponent bf16s; real bf16 data never exceeds 2^17.
    const unsigned short* xu = (const unsigned short*)x;
    const int lane = threadIdx.x & 63;
    const unsigned short s0 = xu[lane * 2];
    const unsigned short s1 = xu[lane * 2 + 1];
    const int big = (((s0 >> 7) & 0xFF) >= 0x90) || (((s1 >> 7) & 0xFF) >= 0x90);
    const bool isf32 = __any(big) != 0;

    if (isf32) run_body<true >(x, Wih, Whh, bih, bhh, Wfc, bfc, out, hbuf, xbuf, hfin);
    else       run_body<false>(x, Wih, Whh, bih, bhh, Wfc, bfc, out, hbuf, xbuf, hfin);
}

extern "C" void kernel_launch(void* const* d_in, const int* in_sizes, int n_in,
                              void* d_out, int out_size, void* d_ws, size_t ws_size,
                              hipStream_t stream) {
    lstm_fused<<<dim3(B_TOT / B_TILE), dim3(256), 0, stream>>>(
        d_in[0], d_in[1], d_in[2], d_in[3], d_in[4], d_in[5], d_in[6], d_out);
}

// Round 8
// 278.404 us; speedup vs baseline: 1.3647x; 1.0368x over previous
//
#include <hip/hip_runtime.h>
#include <stdint.h>

// LSTM fused: B=8192, T=128, I=32, H=64, OUT=8. fp32 internal state, bf16 MFMA.
// R8 = R3's PASSING source with exactly ONE change: hi/lo recurrent split
// removed (12 MFMA/thread-step vs 20; bf16-h quant error ~1e-4..1e-3, fits
// threshold per R2/R3 margin). Everything else byte-identical to R3:
// scalar ldin weight loads, sniff+template dispatcher, xbuf LDS staging.
// NaN ledger: R1/R5/R7 (vector weight loads, plain body) and R6 (K=16 f16)
// all NaN'd; R2/R3 (scalar loads + this dispatcher) passed. Do not reintroduce
// those factors without an isolated A/B.

#define T_STEPS 128
#define ISZ 32
#define HSZ 64
#define B_TOT 8192
#define B_TILE 16
#define T_CHUNK 32
#define HPAD 144

typedef short bf16x8 __attribute__((ext_vector_type(8)));
typedef float f32x4 __attribute__((ext_vector_type(4)));

#define LOG2E 1.44269504088896340736f

__device__ __forceinline__ float bf2f(unsigned short s) {
    union { unsigned int u; float f; } v; v.u = ((unsigned int)s) << 16; return v.f;
}
__device__ __forceinline__ unsigned short f2bf(float f) {
    union { float f; unsigned int u; } v; v.f = f;
    unsigned int u = v.u;
    return (unsigned short)((u + 0x7fffu + ((u >> 16) & 1u)) >> 16);  // RNE
}
// sigmoid = rcp(1 + exp2(-x*log2e)); x->-inf: exp2->inf, rcp->0; x->+inf: 1. Safe.
__device__ __forceinline__ float sigf(float x) {
    return __builtin_amdgcn_rcpf(1.0f + __builtin_amdgcn_exp2f(-LOG2E * x));
}
// tanh = 1 - 2*rcp(1 + exp2(2x*log2e)); +inf -> 1; -inf -> -1. Safe.
__device__ __forceinline__ float tanh_fast(float x) {
    return 1.0f - 2.0f * __builtin_amdgcn_rcpf(1.0f + __builtin_amdgcn_exp2f((2.0f * LOG2E) * x));
}

template <bool F32>
__device__ __forceinline__ float ldin(const void* p, size_t i) {
    if (F32) return ((const float*)p)[i];
    return bf2f(((const unsigned short*)p)[i]);
}

template <bool F32>
__device__ __forceinline__ void run_body(
    const void* xv, const void* Wihv, const void* Whhv, const void* bihv,
    const void* bhhv, const void* Wfcv, const void* bfcv, void* outv,
    unsigned short (&hbuf)[2][B_TILE][HPAD],
    unsigned short (&xbuf)[T_CHUNK][B_TILE][40],
    float (&hfin)[B_TILE][HSZ + 4])
{
    const int tid  = threadIdx.x;
    const int wid  = tid >> 6;
    const int lane = tid & 63;
    const int q    = lane >> 4;   // A/B frag k-quad; C/D row-quad
    const int tn   = lane & 15;   // A: batch row m; B/C: unit col n
    const int u    = wid * 16 + tn;
    const int b0   = blockIdx.x * B_TILE;

    // B-operand weight frags, loaded once (scalar loads — see NaN ledger).
    bf16x8 wf[4][3];
    float bias[4];
    #pragma unroll
    for (int g = 0; g < 4; ++g) {
        const int row = g * HSZ + u;
        #pragma unroll
        for (int j = 0; j < 8; ++j) {
            wf[g][0][j] = (short)f2bf(ldin<F32>(Whhv, row * HSZ + q * 8 + j));
            wf[g][1][j] = (short)f2bf(ldin<F32>(Whhv, row * HSZ + 32 + q * 8 + j));
            wf[g][2][j] = (short)f2bf(ldin<F32>(Wihv, row * ISZ + q * 8 + j));
        }
        bias[g] = ldin<F32>(bihv, row) + ldin<F32>(bhhv, row);
    }

    // h(0) = 0
    for (int i = tid; i < 2 * B_TILE * HPAD; i += 256) ((unsigned short*)hbuf)[i] = 0;

    float cst[4] = {0.f, 0.f, 0.f, 0.f};
    float hl[4]  = {0.f, 0.f, 0.f, 0.f};

    for (int tc = 0; tc < T_STEPS / T_CHUNK; ++tc) {
        // stage x[b0..+16)[tc*32..+32)[0..32) -> xbuf[t][m][k]; prev chunk's
        // reads finished at the last step's barrier, so no barrier needed here.
        if (F32) {
            const float* xf = (const float*)xv;
            for (int idx = tid; idx < B_TILE * T_CHUNK * 4; idx += 256) {
                const int m  = idx >> 7;
                const int rm = idx & 127;
                const int tl = rm >> 2;
                const int ch = rm & 3;
                const size_t base = ((size_t)(b0 + m) * T_STEPS + (tc * T_CHUNK + tl)) * ISZ + ch * 8;
                const f32x4 v0 = *(const f32x4*)(xf + base);
                const f32x4 v1 = *(const f32x4*)(xf + base + 4);
                bf16x8 w;
                #pragma unroll
                for (int j = 0; j < 4; ++j) {
                    w[j]     = (short)f2bf(v0[j]);
                    w[4 + j] = (short)f2bf(v1[j]);
                }
                *(bf16x8*)&xbuf[tl][m][ch * 8] = w;
            }
        } else {
            const unsigned short* xu = (const unsigned short*)xv;
            for (int idx = tid; idx < B_TILE * T_CHUNK * 4; idx += 256) {
                const int m  = idx >> 7;
                const int rm = idx & 127;
                const int tl = rm >> 2;
                const int ch = rm & 3;
                const uint4 v = *(const uint4*)(xu + ((size_t)(b0 + m) * T_STEPS + (tc * T_CHUNK + tl)) * ISZ + ch * 8);
                *(uint4*)&xbuf[tl][m][ch * 8] = v;
            }
        }
        __syncthreads();

        #pragma unroll 2
        for (int tl = 0; tl < T_CHUNK; ++tl) {
            const int t  = tc * T_CHUNK + tl;
            const int rb = t & 1, wb = rb ^ 1;
            // A frags: A[m=tn][k=q*8+j]
            const bf16x8 a0 = *(const bf16x8*)&hbuf[rb][tn][q * 8];       // h k0..31
            const bf16x8 a1 = *(const bf16x8*)&hbuf[rb][tn][32 + q * 8];  // h k32..63
            const bf16x8 ax = *(const bf16x8*)&xbuf[tl][tn][q * 8];       // x

            f32x4 acc[4];
            #pragma unroll
            for (int g = 0; g < 4; ++g) {
                #pragma unroll
                for (int e = 0; e < 4; ++e) acc[g][e] = bias[g];  // bias folded into init
                acc[g] = __builtin_amdgcn_mfma_f32_16x16x32_bf16(a0, wf[g][0], acc[g], 0, 0, 0);
                acc[g] = __builtin_amdgcn_mfma_f32_16x16x32_bf16(a1, wf[g][1], acc[g], 0, 0, 0);
                acc[g] = __builtin_amdgcn_mfma_f32_16x16x32_bf16(ax, wf[g][2], acc[g], 0, 0, 0);
            }
            #pragma unroll
            for (int r = 0; r < 4; ++r) {
                const float gi = sigf(acc[0][r]);
                const float gf = sigf(acc[1][r]);
                const float gg = tanh_fast(acc[2][r]);
                const float go = sigf(acc[3][r]);
                cst[r] = gf * cst[r] + gi * gg;
                const float hv = go * tanh_fast(cst[r]);
                hl[r] = hv;
                const int m = q * 4 + r;  // C/D row = batch
                hbuf[wb][m][u] = f2bf(hv);
            }
            __syncthreads();
        }
    }

    // epilogue: out[b][j] = h_T(fp32) . Wfc[j,:] + bfc[j]
    #pragma unroll
    for (int r = 0; r < 4; ++r) hfin[q * 4 + r][u] = hl[r];
    __syncthreads();
    if (tid < B_TILE * 8) {
        const int m = tid >> 3, j = tid & 7;
        float s = ldin<F32>(bfcv, j);
        #pragma unroll
        for (int k = 0; k < HSZ; ++k) s += hfin[m][k] * ldin<F32>(Wfcv, j * HSZ + k);
        const size_t o = (size_t)(b0 + m) * 8 + j;
        if (F32) ((float*)outv)[o] = s;
        else     ((unsigned short*)outv)[o] = f2bf(s);
    }
}

__global__ __launch_bounds__(256, 2) void lstm_fused(
    const void* __restrict__ x, const void* __restrict__ Wih,
    const void* __restrict__ Whh, const void* __restrict__ bih,
    const void* __restrict__ bhh, const void* __restrict__ Wfc,
    const void* __restrict__ bfc, void* __restrict__ out)
{
    __shared__ unsigned short hbuf[2][B_TILE][HPAD];
    __shared__ unsigned short xbuf[T_CHUNK][B_TILE][40];
    __shared__ float hfin[B_TILE][HSZ + 4];

    // dtype sniff (guard): fp32 data read as uint16 halves has mantissa-garbage
    // halves decoding to huge-exponent bf16s; real bf16 data never exceeds 2^17.
    const unsigned short* xu = (const unsigned short*)x;
    const int lane = threadIdx.x & 63;
    const unsigned short s0 = xu[lane * 2];
    const unsigned short s1 = xu[lane * 2 + 1];
    const int big = (((s0 >> 7) & 0xFF) >= 0x90) || (((s1 >> 7) & 0xFF) >= 0x90);
    const bool isf32 = __any(big) != 0;

    if (isf32) run_body<true >(x, Wih, Whh, bih, bhh, Wfc, bfc, out, hbuf, xbuf, hfin);
    else       run_body<false>(x, Wih, Whh, bih, bhh, Wfc, bfc, out, hbuf, xbuf, hfin);
}

extern "C" void kernel_launch(void* const* d_in, const int* in_sizes, int n_in,
                              void* d_out, int out_size, void* d_ws, size_t ws_size,
                              hipStream_t stream) {
    lstm_fused<<<dim3(B_TOT / B_TILE), dim3(256), 0, stream>>>(
        d_in[0], d_in[1], d_in[2], d_in[3], d_in[4], d_in[5], d_in[6], d_out);
}